// Round 1
// baseline (359855.396 us; speedup 1.0000x reference)
//
#include <hip/hip_runtime.h>
#include <math.h>

#define NWG   256
#define TPB   512          // 8 waves
#define H     1536
#define S_TOT 2048
#define RPW   6            // h rows owned per WG
#define GRW   24           // gate rows per WG (4 gates x 6 rows)
#define OUTP  2048         // probs offset in d_out

struct Params {
  const float* inputs; const float* h_init; const float* c_init;
  const float* W_ih0; const float* W_hh0; const float* b_ih0; const float* b_hh0;
  const float* W_ih1; const float* W_hh1; const float* b_ih1; const float* b_hh1;
  const float* W_lin; const float* b_lin; const float* lookup;
  float* out; float* h0g; float* h1g; unsigned* bar;
};

__device__ __forceinline__ float gload(const float* p) {
  return __hip_atomic_load(p, __ATOMIC_RELAXED, __HIP_MEMORY_SCOPE_AGENT);
}
__device__ __forceinline__ void gstore(float* p, float v) {
  __hip_atomic_store(p, v, __ATOMIC_RELAXED, __HIP_MEMORY_SCOPE_AGENT);
}

// JAX threefry2x32 (20 rounds), bit-exact.
__device__ __forceinline__ void tf2x32(unsigned k0, unsigned k1,
                                       unsigned x0, unsigned x1,
                                       unsigned& o0, unsigned& o1) {
  unsigned ks2 = k0 ^ k1 ^ 0x1BD11BDAu;
  x0 += k0; x1 += k1;
#define TFR(r) { x0 += x1; x1 = ((x1 << r) | (x1 >> (32 - r))); x1 ^= x0; }
  TFR(13) TFR(15) TFR(26) TFR(6)   x0 += k1;  x1 += ks2 + 1u;
  TFR(17) TFR(29) TFR(16) TFR(24)  x0 += ks2; x1 += k0 + 2u;
  TFR(13) TFR(15) TFR(26) TFR(6)   x0 += k0;  x1 += k1 + 3u;
  TFR(17) TFR(29) TFR(16) TFR(24)  x0 += k1;  x1 += ks2 + 4u;
  TFR(13) TFR(15) TFR(26) TFR(6)   x0 += ks2; x1 += k0 + 5u;
#undef TFR
  o0 = x0; o1 = x1;
}

__device__ __forceinline__ double bsum64(double v) {
#pragma unroll
  for (int o = 32; o > 0; o >>= 1) v += __shfl_xor(v, o);
  return v;
}

__device__ __forceinline__ float sigf(float x) { return 1.0f / (1.0f + expf(-x)); }

// All-to-all flag barrier. Monotone compare: safe vs 0xAA poison and vs a fast
// WG already publishing epoch e+1 while a slow one still polls epoch e.
__device__ __forceinline__ void flagbar(unsigned* bar, unsigned e, int tid, int wg) {
  __threadfence();      // make this thread's agent stores visible device-wide
  __syncthreads();      // everyone's data published before flag
  if (tid == 0)
    __hip_atomic_store(&bar[wg], e, __ATOMIC_RELEASE, __HIP_MEMORY_SCOPE_AGENT);
  if (tid < NWG) {
    while ((int)(__hip_atomic_load(&bar[tid], __ATOMIC_ACQUIRE,
                                   __HIP_MEMORY_SCOPE_AGENT) - e) < 0) { }
  }
  __syncthreads();
}

__global__ __launch_bounds__(TPB, 2)
void lstm_persistent(Params P) {
  const int tid  = threadIdx.x;
  const int wg   = blockIdx.x;
  const int wv   = tid >> 6;
  const int lane = tid & 63;

  __shared__ float s_Wih0[GRW * 32];
  __shared__ float s_h0[H], s_h1[H];
  __shared__ float s_bih0[GRW], s_bhh0[GRW], s_bih1[GRW], s_bhh1[GRW];
  __shared__ float s_hh1dot[GRW], s_gate[GRW];
  __shared__ float s_x[32];
  __shared__ float s_c0[RPW], s_c1[RPW];
  __shared__ float s_logits[16];
  __shared__ float s_blin[10], s_lookup[10];
  __shared__ int   s_action;

  // ---------------- init ----------------
  for (int k = tid; k < GRW * 32; k += TPB) {
    int idx = k >> 5, kk = k & 31;
    int q = idx / RPW, u = idx % RPW;
    int gr = q * H + wg * RPW + u;
    s_Wih0[k] = P.W_ih0[gr * 32 + kk];
  }
  if (tid < GRW) {
    int q = tid / RPW, u = tid % RPW;
    int gr = q * H + wg * RPW + u;
    s_bih0[tid] = P.b_ih0[gr]; s_bhh0[tid] = P.b_hh0[gr];
    s_bih1[tid] = P.b_ih1[gr]; s_bhh1[tid] = P.b_hh1[gr];
  }
  if (tid < 10) { s_blin[tid] = P.b_lin[tid]; s_lookup[tid] = P.lookup[tid]; }
  if (tid < RPW) {
    s_c0[tid] = P.c_init[wg * RPW + tid];
    s_c1[tid] = P.c_init[H + wg * RPW + tid];
    gstore(P.h0g + wg * RPW + tid, P.h_init[wg * RPW + tid]);
    gstore(P.h1g + wg * RPW + tid, P.h_init[H + wg * RPW + tid]);
  }

  // weight registers: wr[0..2]=W_hh0 slots, wr[3..5]=W_hh1, wr[6..8]=W_ih1
  float wr[9][24];
#pragma unroll
  for (int slot = 0; slot < 3; ++slot) {
    int idx = wv * 3 + slot;
    int q = idx / RPW, u = idx % RPW;
    int gr = q * H + wg * RPW + u;
    const float* r0 = P.W_hh0 + (size_t)gr * H;
    const float* r1 = P.W_hh1 + (size_t)gr * H;
    const float* r2 = P.W_ih1 + (size_t)gr * H;
#pragma unroll
    for (int t = 0; t < 24; ++t) {
      int off = lane + (t << 6);
      wr[slot][t] = r0[off]; wr[3 + slot][t] = r1[off]; wr[6 + slot][t] = r2[off];
    }
  }
  // W_lin rows wv and wv+8 in registers (logits computed redundantly per WG)
  float wl[2][24];
#pragma unroll
  for (int p2 = 0; p2 < 2; ++p2) {
    int l = wv + 8 * p2;
#pragma unroll
    for (int t = 0; t < 24; ++t)
      wl[p2][t] = (l < 10) ? P.W_lin[l * H + lane + (t << 6)] : 0.0f;
  }

  unsigned ep = 1;
  flagbar(P.bar, ep++, tid, wg);

  // ---------------- main sequential loop ----------------
  for (int s = 0; s <= S_TOT; ++s) {
    // stage h0prev / h1prev
#pragma unroll
    for (int r = 0; r < 3; ++r) {
      int k = tid + r * TPB;
      s_h0[k] = gload(P.h0g + k);
      s_h1[k] = gload(P.h1g + k);
    }
    __syncthreads();

    if (s > 0) {
      int sp = s - 1;
      // logits = h1prev @ W_lin.T + b_lin  (redundant per WG, fp64 acc)
#pragma unroll
      for (int p2 = 0; p2 < 2; ++p2) {
        int l = wv + 8 * p2;
        if (l < 10) {
          double acc = 0.0;
#pragma unroll
          for (int t = 0; t < 24; ++t)
            acc += (double)wl[p2][t] * (double)s_h1[lane + (t << 6)];
          acc = bsum64(acc);
          if (lane == 0) s_logits[l] = __fadd_rn((float)acc, s_blin[l]);
        }
      }
      __syncthreads();

      if (wv == 0) {
        // key_sp = threefry(key(42)=(0,42); 0, sp)   [partitionable split]
        unsigned kk0, kk1; tf2x32(0u, 42u, 0u, (unsigned)sp, kk0, kk1);
        // bits[c] = o0 ^ o1 of threefry(key_sp; 0, c) [partitionable bits]
        unsigned b1, b2; tf2x32(kk0, kk1, 0u, (unsigned)lane, b1, b2);
        unsigned bits = b1 ^ b2;
        float uraw = __fsub_rn(__uint_as_float((bits >> 9) | 0x3F800000u), 1.0f);
        const float TINY = 1.17549435e-38f;
        float u  = fmaxf(TINY, __fadd_rn(uraw, TINY));
        float gum = -logf(-logf(u));
        float lg = (lane < 10) ? s_logits[lane] : 0.0f;
        float y  = (lane < 10) ? __fadd_rn(lg, gum) : -INFINITY;
        int ai = lane;
#pragma unroll
        for (int o = 1; o < 16; o <<= 1) {
          float oy = __shfl_xor(y, o); int oi = __shfl_xor(ai, o);
          if (oy > y || (oy == y && oi < ai)) { y = oy; ai = oi; }
        }
        // softmax (jax.nn.softmax: exp(x - max) / sum)
        float lm = (lane < 10) ? lg : -INFINITY;
#pragma unroll
        for (int o = 1; o < 16; o <<= 1) lm = fmaxf(lm, __shfl_xor(lm, o));
        float e2 = (lane < 10) ? expf(__fsub_rn(lg, lm)) : 0.0f;
        float ssum = e2;
#pragma unroll
        for (int o = 1; o < 16; o <<= 1) ssum = __fadd_rn(ssum, __shfl_xor(ssum, o));
        if (lane == 0) s_action = ai;
        if (wg == 0) {
          if (lane < 10) P.out[OUTP + sp * 10 + lane] = e2 / ssum;
          if (lane == 0) P.out[sp] = (float)ai;
        }
      }
      __syncthreads();
      if (tid == 0) {
        int jp = sp & 31;
        if (jp != 0) s_x[jp] = __fmul_rn(s_x[jp], s_lookup[s_action]);
      }
      __syncthreads();
    }

    if (s == S_TOT) break;
    int ii = s >> 5, jj = s & 31;
    if (jj == 0 && tid < 32) s_x[tid] = P.inputs[ii * 32 + tid];
    __syncthreads();

    // ---------- phase 1: gates0 (W_ih0·x + W_hh0·h0prev) and W_hh1·h1prev ----------
    {
      double a0 = 0, a1 = 0, a2 = 0, b0 = 0, b1 = 0, b2 = 0;
#pragma unroll
      for (int t = 0; t < 24; ++t) {
        int off = lane + (t << 6);
        double h0v = (double)s_h0[off];
        double h1v = (double)s_h1[off];
        a0 += (double)wr[0][t] * h0v;
        a1 += (double)wr[1][t] * h0v;
        a2 += (double)wr[2][t] * h0v;
        b0 += (double)wr[3][t] * h1v;
        b1 += (double)wr[4][t] * h1v;
        b2 += (double)wr[5][t] * h1v;
      }
      a0 = bsum64(a0); a1 = bsum64(a1); a2 = bsum64(a2);
      b0 = bsum64(b0); b1 = bsum64(b1); b2 = bsum64(b2);
      double xa[3];
#pragma unroll
      for (int slot = 0; slot < 3; ++slot) {
        int idx = wv * 3 + slot;
        double pp = (lane < 32)
          ? (double)s_Wih0[(idx << 5) + lane] * (double)s_x[lane] : 0.0;
#pragma unroll
        for (int o = 16; o > 0; o >>= 1) pp += __shfl_xor(pp, o);
        xa[slot] = pp;
      }
      if (lane == 0) {
        double aa[3] = {a0, a1, a2}, bb[3] = {b0, b1, b2};
#pragma unroll
        for (int slot = 0; slot < 3; ++slot) {
          int idx = wv * 3 + slot;
          // ((x·Wih + b_ih) + h·Whh) + b_hh  — reference add order
          float g0 = __fadd_rn(__fadd_rn(__fadd_rn((float)xa[slot], s_bih0[idx]),
                                         (float)aa[slot]), s_bhh0[idx]);
          s_gate[idx]   = g0;
          s_hh1dot[idx] = (float)bb[slot];
        }
      }
    }
    __syncthreads();
    if (tid < RPW) {
      int u = tid;
      float gi = s_gate[u], gf = s_gate[6 + u], gg = s_gate[12 + u], go = s_gate[18 + u];
      float c = __fadd_rn(__fmul_rn(sigf(gf), s_c0[u]), __fmul_rn(sigf(gi), tanhf(gg)));
      s_c0[u] = c;
      float h = __fmul_rn(sigf(go), tanhf(c));
      gstore(P.h0g + wg * RPW + u, h);
    }
    flagbar(P.bar, ep++, tid, wg);

    // ---------- phase 2: gates1 = W_ih1·h0 + (stashed W_hh1·h1prev) ----------
#pragma unroll
    for (int r = 0; r < 3; ++r) {
      int k = tid + r * TPB;
      s_h0[k] = gload(P.h0g + k);
    }
    __syncthreads();
    {
      double a0 = 0, a1 = 0, a2 = 0;
#pragma unroll
      for (int t = 0; t < 24; ++t) {
        double hv = (double)s_h0[lane + (t << 6)];
        a0 += (double)wr[6][t] * hv;
        a1 += (double)wr[7][t] * hv;
        a2 += (double)wr[8][t] * hv;
      }
      a0 = bsum64(a0); a1 = bsum64(a1); a2 = bsum64(a2);
      if (lane == 0) {
        double aa[3] = {a0, a1, a2};
#pragma unroll
        for (int slot = 0; slot < 3; ++slot) {
          int idx = wv * 3 + slot;
          s_gate[idx] = __fadd_rn(__fadd_rn(__fadd_rn((float)aa[slot], s_bih1[idx]),
                                            s_hh1dot[idx]), s_bhh1[idx]);
        }
      }
    }
    __syncthreads();
    if (tid < RPW) {
      int u = tid;
      float gi = s_gate[u], gf = s_gate[6 + u], gg = s_gate[12 + u], go = s_gate[18 + u];
      float c = __fadd_rn(__fmul_rn(sigf(gf), s_c1[u]), __fmul_rn(sigf(gi), tanhf(gg)));
      s_c1[u] = c;
      float h = __fmul_rn(sigf(go), tanhf(c));
      gstore(P.h1g + wg * RPW + u, h);
    }
    flagbar(P.bar, ep++, tid, wg);
  }
}

extern "C" void kernel_launch(void* const* d_in, const int* in_sizes, int n_in,
                              void* d_out, int out_size, void* d_ws, size_t ws_size,
                              hipStream_t stream) {
  (void)in_sizes; (void)n_in; (void)out_size; (void)ws_size;
  Params p;
  p.inputs = (const float*)d_in[0];
  p.h_init = (const float*)d_in[1];
  p.c_init = (const float*)d_in[2];
  p.W_ih0  = (const float*)d_in[3];
  p.W_hh0  = (const float*)d_in[4];
  p.b_ih0  = (const float*)d_in[5];
  p.b_hh0  = (const float*)d_in[6];
  p.W_ih1  = (const float*)d_in[7];
  p.W_hh1  = (const float*)d_in[8];
  p.b_ih1  = (const float*)d_in[9];
  p.b_hh1  = (const float*)d_in[10];
  p.W_lin  = (const float*)d_in[11];
  p.b_lin  = (const float*)d_in[12];
  p.lookup = (const float*)d_in[13];
  p.out    = (float*)d_out;
  float* ws = (float*)d_ws;
  p.h0g = ws;
  p.h1g = ws + H;
  p.bar = (unsigned*)(ws + 2 * H);
  hipLaunchKernelGGL(lstm_persistent, dim3(NWG), dim3(TPB), 0, stream, p);
}

// Round 3
// 180056.213 us; speedup vs baseline: 1.9986x; 1.9986x over previous
//
#include <hip/hip_runtime.h>
#include <math.h>

#define NWG   256
#define TPB   512          // 8 waves
#define H     1536
#define S_TOT 2048
#define RPW   6            // h rows owned per WG
#define GRW   24           // gate rows per WG (4 gates x 6 rows)
#define OUTP  2048         // probs offset in d_out

// dynamic LDS: W_lin (10*1536) + W_ih1 slot-2 rows (8*1536)
#define SMEM_FLOATS (10 * H + 8 * H)
#define SMEM_BYTES  (SMEM_FLOATS * 4)

struct Params {
  const float* inputs; const float* h_init; const float* c_init;
  const float* W_ih0; const float* W_hh0; const float* b_ih0; const float* b_hh0;
  const float* W_ih1; const float* W_hh1; const float* b_ih1; const float* b_hh1;
  const float* W_lin; const float* b_lin; const float* lookup;
  float* out; float* h0g; float* h1g; unsigned* bar;
};

__device__ __forceinline__ float gload(const float* p) {
  return __hip_atomic_load(p, __ATOMIC_RELAXED, __HIP_MEMORY_SCOPE_AGENT);
}
__device__ __forceinline__ void gstore(float* p, float v) {
  __hip_atomic_store(p, v, __ATOMIC_RELAXED, __HIP_MEMORY_SCOPE_AGENT);
}

// JAX threefry2x32 (20 rounds), bit-exact.
__device__ __forceinline__ void tf2x32(unsigned k0, unsigned k1,
                                       unsigned x0, unsigned x1,
                                       unsigned& o0, unsigned& o1) {
  unsigned ks2 = k0 ^ k1 ^ 0x1BD11BDAu;
  x0 += k0; x1 += k1;
#define TFR(r) { x0 += x1; x1 = ((x1 << r) | (x1 >> (32 - r))); x1 ^= x0; }
  TFR(13) TFR(15) TFR(26) TFR(6)   x0 += k1;  x1 += ks2 + 1u;
  TFR(17) TFR(29) TFR(16) TFR(24)  x0 += ks2; x1 += k0 + 2u;
  TFR(13) TFR(15) TFR(26) TFR(6)   x0 += k0;  x1 += k1 + 3u;
  TFR(17) TFR(29) TFR(16) TFR(24)  x0 += k1;  x1 += ks2 + 4u;
  TFR(13) TFR(15) TFR(26) TFR(6)   x0 += ks2; x1 += k0 + 5u;
#undef TFR
  o0 = x0; o1 = x1;
}

__device__ __forceinline__ double bsum64(double v) {
#pragma unroll
  for (int o = 32; o > 0; o >>= 1) v += __shfl_xor(v, o);
  return v;
}

__device__ __forceinline__ float sigf(float x) { return 1.0f / (1.0f + expf(-x)); }

// All-to-all flag barrier. Publisher: release fence (waitcnt + L2 writeback)
// + release store. Pollers: wave 0 only, RELAXED loads in the spin loop, one
// agent acquire fence at exit. Monotone >= compare: safe vs 0xAA poison and vs
// fast WGs already publishing epoch e+1.
// NOTE sign-bit algebra: lane is done only when ALL four deltas >= 0, i.e. the
// OR of the deltas has a clear sign bit. (Round-2 bug: used AND, which is
// non-negative if ANY delta is — barrier released early, raced on h.)
__device__ __forceinline__ void flagbar(unsigned* bar, unsigned e, int tid, int wg) {
  __builtin_amdgcn_fence(__ATOMIC_RELEASE, "agent");
  __syncthreads();      // everyone's data published before flag
  if (tid == 0)
    __hip_atomic_store(&bar[wg], e, __ATOMIC_RELEASE, __HIP_MEMORY_SCOPE_AGENT);
  if (tid < 64) {
    const unsigned* f = bar + tid * 4;
    bool done;
    do {
      int d0 = (int)(__hip_atomic_load(f + 0, __ATOMIC_RELAXED, __HIP_MEMORY_SCOPE_AGENT) - e);
      int d1 = (int)(__hip_atomic_load(f + 1, __ATOMIC_RELAXED, __HIP_MEMORY_SCOPE_AGENT) - e);
      int d2 = (int)(__hip_atomic_load(f + 2, __ATOMIC_RELAXED, __HIP_MEMORY_SCOPE_AGENT) - e);
      int d3 = (int)(__hip_atomic_load(f + 3, __ATOMIC_RELAXED, __HIP_MEMORY_SCOPE_AGENT) - e);
      done = ((d0 | d1 | d2 | d3) >= 0);   // all >= 0
    } while (!__all(done));
    __builtin_amdgcn_fence(__ATOMIC_ACQUIRE, "agent");
  }
  __syncthreads();
}

__global__ __launch_bounds__(TPB, 2)
void lstm_persistent(Params P) {
  const int tid  = threadIdx.x;
  const int wg   = blockIdx.x;
  const int wv   = tid >> 6;
  const int lane = tid & 63;

  extern __shared__ float smem[];
  float* s_Wlin = smem;            // 10*H, row-major [l*H + col]
  float* s_W3   = smem + 10 * H;   // 8*H : W_ih1 rows for idx = wv*3+2, [wv*H + col]

  __shared__ float s_Wih0[GRW * 32];
  __shared__ float s_h0[H], s_h1[H];
  __shared__ float s_bih0[GRW], s_bhh0[GRW], s_bih1[GRW], s_bhh1[GRW];
  __shared__ float s_hh1dot[GRW], s_gate[GRW];
  __shared__ float s_x[32];
  __shared__ float s_c0[RPW], s_c1[RPW];
  __shared__ float s_logits[16];
  __shared__ float s_blin[10], s_lookup[10];
  __shared__ int   s_action;

  // ---------------- init ----------------
  for (int k = tid; k < GRW * 32; k += TPB) {
    int idx = k >> 5, kk = k & 31;
    int q = idx / RPW, u = idx % RPW;
    int gr = q * H + wg * RPW + u;
    s_Wih0[k] = P.W_ih0[gr * 32 + kk];
  }
  for (int k = tid; k < 10 * H; k += TPB) s_Wlin[k] = P.W_lin[k];
  for (int k = tid; k < 8 * H; k += TPB) {
    int w8 = k / H, col = k % H;
    int idx = w8 * 3 + 2;                 // W_ih1 slot-2 row of wave w8
    int q = idx / RPW, u = idx % RPW;
    int gr = q * H + wg * RPW + u;
    s_W3[k] = P.W_ih1[(size_t)gr * H + col];
  }
  if (tid < GRW) {
    int q = tid / RPW, u = tid % RPW;
    int gr = q * H + wg * RPW + u;
    s_bih0[tid] = P.b_ih0[gr]; s_bhh0[tid] = P.b_hh0[gr];
    s_bih1[tid] = P.b_ih1[gr]; s_bhh1[tid] = P.b_hh1[gr];
  }
  if (tid < 10) { s_blin[tid] = P.b_lin[tid]; s_lookup[tid] = P.lookup[tid]; }
  if (tid < RPW) {
    s_c0[tid] = P.c_init[wg * RPW + tid];
    s_c1[tid] = P.c_init[H + wg * RPW + tid];
    gstore(P.h0g + wg * RPW + tid, P.h_init[wg * RPW + tid]);
    gstore(P.h1g + wg * RPW + tid, P.h_init[H + wg * RPW + tid]);
  }

  // weight registers (192 floats): wr[0..2]=W_hh0, wr[3..5]=W_hh1, wr[6..7]=W_ih1 slots 0-1
  float wr[8][24];
#pragma unroll
  for (int slot = 0; slot < 3; ++slot) {
    int idx = wv * 3 + slot;
    int q = idx / RPW, u = idx % RPW;
    int gr = q * H + wg * RPW + u;
    const float* r0 = P.W_hh0 + (size_t)gr * H;
    const float* r1 = P.W_hh1 + (size_t)gr * H;
#pragma unroll
    for (int t = 0; t < 24; ++t) {
      int off = lane + (t << 6);
      wr[slot][t] = r0[off]; wr[3 + slot][t] = r1[off];
    }
  }
#pragma unroll
  for (int slot = 0; slot < 2; ++slot) {
    int idx = wv * 3 + slot;
    int q = idx / RPW, u = idx % RPW;
    int gr = q * H + wg * RPW + u;
    const float* r2 = P.W_ih1 + (size_t)gr * H;
#pragma unroll
    for (int t = 0; t < 24; ++t) wr[6 + slot][t] = r2[lane + (t << 6)];
  }

  unsigned ep = 1;
  flagbar(P.bar, ep++, tid, wg);

  // ---------------- main sequential loop ----------------
  for (int s = 0; s <= S_TOT; ++s) {
    // stage h0prev / h1prev
#pragma unroll
    for (int r = 0; r < 3; ++r) {
      int k = tid + r * TPB;
      s_h0[k] = gload(P.h0g + k);
      s_h1[k] = gload(P.h1g + k);
    }
    __syncthreads();

    if (s > 0) {
      int sp = s - 1;
      // logits = h1prev @ W_lin.T + b_lin  (redundant per WG, fp64 acc)
#pragma unroll
      for (int p2 = 0; p2 < 2; ++p2) {
        int l = wv + 8 * p2;
        if (l < 10) {
          double acc = 0.0;
#pragma unroll
          for (int t = 0; t < 24; ++t) {
            int off = lane + (t << 6);
            acc += (double)s_Wlin[l * H + off] * (double)s_h1[off];
          }
          acc = bsum64(acc);
          if (lane == 0) s_logits[l] = __fadd_rn((float)acc, s_blin[l]);
        }
      }
      __syncthreads();

      if (wv == 0) {
        // key_sp = threefry(key(42)=(0,42); 0, sp)   [partitionable split]
        unsigned kk0, kk1; tf2x32(0u, 42u, 0u, (unsigned)sp, kk0, kk1);
        unsigned b1, b2; tf2x32(kk0, kk1, 0u, (unsigned)lane, b1, b2);
        unsigned bits = b1 ^ b2;
        float uraw = __fsub_rn(__uint_as_float((bits >> 9) | 0x3F800000u), 1.0f);
        const float TINY = 1.17549435e-38f;
        float u  = fmaxf(TINY, __fadd_rn(uraw, TINY));
        float gum = -logf(-logf(u));
        float lg = (lane < 10) ? s_logits[lane] : 0.0f;
        float y  = (lane < 10) ? __fadd_rn(lg, gum) : -INFINITY;
        int ai = lane;
#pragma unroll
        for (int o = 1; o < 16; o <<= 1) {
          float oy = __shfl_xor(y, o); int oi = __shfl_xor(ai, o);
          if (oy > y || (oy == y && oi < ai)) { y = oy; ai = oi; }
        }
        float lm = (lane < 10) ? lg : -INFINITY;
#pragma unroll
        for (int o = 1; o < 16; o <<= 1) lm = fmaxf(lm, __shfl_xor(lm, o));
        float e2 = (lane < 10) ? expf(__fsub_rn(lg, lm)) : 0.0f;
        float ssum = e2;
#pragma unroll
        for (int o = 1; o < 16; o <<= 1) ssum = __fadd_rn(ssum, __shfl_xor(ssum, o));
        if (lane == 0) s_action = ai;
        if (wg == 0) {
          if (lane < 10) P.out[OUTP + sp * 10 + lane] = e2 / ssum;
          if (lane == 0) P.out[sp] = (float)ai;
        }
      }
      __syncthreads();
      if (tid == 0) {
        int jp = sp & 31;
        if (jp != 0) s_x[jp] = __fmul_rn(s_x[jp], s_lookup[s_action]);
      }
      __syncthreads();
    }

    if (s == S_TOT) break;
    int ii = s >> 5, jj = s & 31;
    if (jj == 0 && tid < 32) s_x[tid] = P.inputs[ii * 32 + tid];
    __syncthreads();

    // ---------- phase 1: gates0 (W_ih0·x + W_hh0·h0prev) and W_hh1·h1prev ----------
    {
      double a0 = 0, a1 = 0, a2 = 0, b0 = 0, b1 = 0, b2 = 0;
#pragma unroll
      for (int t = 0; t < 24; ++t) {
        int off = lane + (t << 6);
        double h0v = (double)s_h0[off];
        double h1v = (double)s_h1[off];
        a0 += (double)wr[0][t] * h0v;
        a1 += (double)wr[1][t] * h0v;
        a2 += (double)wr[2][t] * h0v;
        b0 += (double)wr[3][t] * h1v;
        b1 += (double)wr[4][t] * h1v;
        b2 += (double)wr[5][t] * h1v;
      }
      a0 = bsum64(a0); a1 = bsum64(a1); a2 = bsum64(a2);
      b0 = bsum64(b0); b1 = bsum64(b1); b2 = bsum64(b2);
      double xa[3];
#pragma unroll
      for (int slot = 0; slot < 3; ++slot) {
        int idx = wv * 3 + slot;
        double pp = (lane < 32)
          ? (double)s_Wih0[(idx << 5) + lane] * (double)s_x[lane] : 0.0;
#pragma unroll
        for (int o = 16; o > 0; o >>= 1) pp += __shfl_xor(pp, o);
        xa[slot] = pp;
      }
      if (lane == 0) {
        double aa[3] = {a0, a1, a2}, bb[3] = {b0, b1, b2};
#pragma unroll
        for (int slot = 0; slot < 3; ++slot) {
          int idx = wv * 3 + slot;
          float g0 = __fadd_rn(__fadd_rn(__fadd_rn((float)xa[slot], s_bih0[idx]),
                                         (float)aa[slot]), s_bhh0[idx]);
          s_gate[idx]   = g0;
          s_hh1dot[idx] = (float)bb[slot];
        }
      }
    }
    __syncthreads();
    if (tid < RPW) {
      int u = tid;
      float gi = s_gate[u], gf = s_gate[6 + u], gg = s_gate[12 + u], go = s_gate[18 + u];
      float c = __fadd_rn(__fmul_rn(sigf(gf), s_c0[u]), __fmul_rn(sigf(gi), tanhf(gg)));
      s_c0[u] = c;
      float h = __fmul_rn(sigf(go), tanhf(c));
      gstore(P.h0g + wg * RPW + u, h);
    }
    flagbar(P.bar, ep++, tid, wg);

    // ---------- phase 2: gates1 = W_ih1·h0 + (stashed W_hh1·h1prev) ----------
#pragma unroll
    for (int r = 0; r < 3; ++r) {
      int k = tid + r * TPB;
      s_h0[k] = gload(P.h0g + k);
    }
    __syncthreads();
    {
      double a0 = 0, a1 = 0, a2 = 0;
#pragma unroll
      for (int t = 0; t < 24; ++t) {
        int off = lane + (t << 6);
        double hv = (double)s_h0[off];
        a0 += (double)wr[6][t] * hv;
        a1 += (double)wr[7][t] * hv;
        a2 += (double)s_W3[wv * H + off] * hv;
      }
      a0 = bsum64(a0); a1 = bsum64(a1); a2 = bsum64(a2);
      if (lane == 0) {
        double aa[3] = {a0, a1, a2};
#pragma unroll
        for (int slot = 0; slot < 3; ++slot) {
          int idx = wv * 3 + slot;
          s_gate[idx] = __fadd_rn(__fadd_rn(__fadd_rn((float)aa[slot], s_bih1[idx]),
                                            s_hh1dot[idx]), s_bhh1[idx]);
        }
      }
    }
    __syncthreads();
    if (tid < RPW) {
      int u = tid;
      float gi = s_gate[u], gf = s_gate[6 + u], gg = s_gate[12 + u], go = s_gate[18 + u];
      float c = __fadd_rn(__fmul_rn(sigf(gf), s_c1[u]), __fmul_rn(sigf(gi), tanhf(gg)));
      s_c1[u] = c;
      float h = __fmul_rn(sigf(go), tanhf(c));
      gstore(P.h1g + wg * RPW + u, h);
    }
    flagbar(P.bar, ep++, tid, wg);
  }
}

extern "C" void kernel_launch(void* const* d_in, const int* in_sizes, int n_in,
                              void* d_out, int out_size, void* d_ws, size_t ws_size,
                              hipStream_t stream) {
  (void)in_sizes; (void)n_in; (void)out_size; (void)ws_size;
  Params p;
  p.inputs = (const float*)d_in[0];
  p.h_init = (const float*)d_in[1];
  p.c_init = (const float*)d_in[2];
  p.W_ih0  = (const float*)d_in[3];
  p.W_hh0  = (const float*)d_in[4];
  p.b_ih0  = (const float*)d_in[5];
  p.b_hh0  = (const float*)d_in[6];
  p.W_ih1  = (const float*)d_in[7];
  p.W_hh1  = (const float*)d_in[8];
  p.b_ih1  = (const float*)d_in[9];
  p.b_hh1  = (const float*)d_in[10];
  p.W_lin  = (const float*)d_in[11];
  p.b_lin  = (const float*)d_in[12];
  p.lookup = (const float*)d_in[13];
  p.out    = (float*)d_out;
  float* ws = (float*)d_ws;
  p.h0g = ws;
  p.h1g = ws + H;
  p.bar = (unsigned*)(ws + 2 * H);

  // opt-in for >64 KB dynamic LDS (idempotent; host-side, graph-capture safe)
  hipFuncSetAttribute((const void*)lstm_persistent,
                      hipFuncAttributeMaxDynamicSharedMemorySize, SMEM_BYTES);
  hipLaunchKernelGGL(lstm_persistent, dim3(NWG), dim3(TPB), SMEM_BYTES, stream, p);
}

// Round 4
// 179809.253 us; speedup vs baseline: 2.0013x; 1.0014x over previous
//
#include <hip/hip_runtime.h>
#include <math.h>

#define NWG   256
#define TPB   512          // 8 waves
#define H     1536
#define S_TOT 2048
#define RPW   6            // h rows owned per WG
#define GRW   24           // gate rows per WG (4 gates x 6 rows)
#define OUTP  2048         // probs offset in d_out

// dynamic LDS: W_lin (10*1536) + W_ih1 slot-2 rows (8*1536)
#define SMEM_FLOATS (10 * H + 8 * H)
#define SMEM_BYTES  (SMEM_FLOATS * 4)

struct Params {
  const float* inputs; const float* h_init; const float* c_init;
  const float* W_ih0; const float* W_hh0; const float* b_ih0; const float* b_hh0;
  const float* W_ih1; const float* W_hh1; const float* b_ih1; const float* b_hh1;
  const float* W_lin; const float* b_lin; const float* lookup;
  float* out; float* h0g; float* h1g; unsigned* bar;
};

__device__ __forceinline__ float gload(const float* p) {
  return __hip_atomic_load(p, __ATOMIC_RELAXED, __HIP_MEMORY_SCOPE_AGENT);
}
__device__ __forceinline__ void gstore(float* p, float v) {
  __hip_atomic_store(p, v, __ATOMIC_RELAXED, __HIP_MEMORY_SCOPE_AGENT);
}

// JAX threefry2x32 (20 rounds), bit-exact.
__device__ __forceinline__ void tf2x32(unsigned k0, unsigned k1,
                                       unsigned x0, unsigned x1,
                                       unsigned& o0, unsigned& o1) {
  unsigned ks2 = k0 ^ k1 ^ 0x1BD11BDAu;
  x0 += k0; x1 += k1;
#define TFR(r) { x0 += x1; x1 = ((x1 << r) | (x1 >> (32 - r))); x1 ^= x0; }
  TFR(13) TFR(15) TFR(26) TFR(6)   x0 += k1;  x1 += ks2 + 1u;
  TFR(17) TFR(29) TFR(16) TFR(24)  x0 += ks2; x1 += k0 + 2u;
  TFR(13) TFR(15) TFR(26) TFR(6)   x0 += k0;  x1 += k1 + 3u;
  TFR(17) TFR(29) TFR(16) TFR(24)  x0 += k1;  x1 += ks2 + 4u;
  TFR(13) TFR(15) TFR(26) TFR(6)   x0 += ks2; x1 += k0 + 5u;
#undef TFR
  o0 = x0; o1 = x1;
}

__device__ __forceinline__ double bsum64(double v) {
#pragma unroll
  for (int o = 32; o > 0; o >>= 1) v += __shfl_xor(v, o);
  return v;
}

__device__ __forceinline__ float sigf(float x) { return 1.0f / (1.0f + expf(-x)); }

// All-to-all flag barrier. Publisher: release fence + release store. Pollers:
// wave 0 only, RELAXED loads in the spin loop, one agent acquire fence at
// exit. Monotone >= compare (via sign bit of OR of deltas): safe vs 0xAA
// poison and vs fast WGs already publishing epoch e+1.
__device__ __forceinline__ void flagbar(unsigned* bar, unsigned e, int tid, int wg) {
  __builtin_amdgcn_fence(__ATOMIC_RELEASE, "agent");
  __syncthreads();      // everyone's data published before flag
  if (tid == 0)
    __hip_atomic_store(&bar[wg], e, __ATOMIC_RELEASE, __HIP_MEMORY_SCOPE_AGENT);
  if (tid < 64) {
    const unsigned* f = bar + tid * 4;
    bool done;
    do {
      int d0 = (int)(__hip_atomic_load(f + 0, __ATOMIC_RELAXED, __HIP_MEMORY_SCOPE_AGENT) - e);
      int d1 = (int)(__hip_atomic_load(f + 1, __ATOMIC_RELAXED, __HIP_MEMORY_SCOPE_AGENT) - e);
      int d2 = (int)(__hip_atomic_load(f + 2, __ATOMIC_RELAXED, __HIP_MEMORY_SCOPE_AGENT) - e);
      int d3 = (int)(__hip_atomic_load(f + 3, __ATOMIC_RELAXED, __HIP_MEMORY_SCOPE_AGENT) - e);
      done = ((d0 | d1 | d2 | d3) >= 0);   // all >= 0
    } while (!__all(done));
    __builtin_amdgcn_fence(__ATOMIC_ACQUIRE, "agent");
  }
  __syncthreads();
}

// __launch_bounds__ 2nd arg: observed (rounds 1/3) this compiler treats it
// CUDA-style as min BLOCKS/CU: (512,2) -> 16 waves/CU -> 128-VGPR cap -> the
// 192-float wr[] array spilled to scratch (FETCH_SIZE 115 GB of spill reads).
// (512,1) -> 8 waves/CU -> 256-VGPR cap -> wr[] fits in registers.
__global__ __launch_bounds__(TPB, 1)
void lstm_persistent(Params P) {
  const int tid  = threadIdx.x;
  const int wg   = blockIdx.x;
  const int wv   = tid >> 6;
  const int lane = tid & 63;

  extern __shared__ float smem[];
  float* s_Wlin = smem;            // 10*H, row-major [l*H + col]
  float* s_W3   = smem + 10 * H;   // 8*H : W_ih1 rows for idx = wv*3+2, [wv*H + col]

  __shared__ float s_Wih0[GRW * 32];
  __shared__ float s_h0[H], s_h1[H];
  __shared__ float s_bih0[GRW], s_bhh0[GRW], s_bih1[GRW], s_bhh1[GRW];
  __shared__ float s_hh1dot[GRW], s_gate[GRW];
  __shared__ float s_x[32];
  __shared__ float s_c0[RPW], s_c1[RPW];
  __shared__ float s_logits[16];
  __shared__ float s_blin[10], s_lookup[10];
  __shared__ int   s_action;

  // ---------------- init ----------------
  for (int k = tid; k < GRW * 32; k += TPB) {
    int idx = k >> 5, kk = k & 31;
    int q = idx / RPW, u = idx % RPW;
    int gr = q * H + wg * RPW + u;
    s_Wih0[k] = P.W_ih0[gr * 32 + kk];
  }
  for (int k = tid; k < 10 * H; k += TPB) s_Wlin[k] = P.W_lin[k];
  for (int k = tid; k < 8 * H; k += TPB) {
    int w8 = k / H, col = k % H;
    int idx = w8 * 3 + 2;                 // W_ih1 slot-2 row of wave w8
    int q = idx / RPW, u = idx % RPW;
    int gr = q * H + wg * RPW + u;
    s_W3[k] = P.W_ih1[(size_t)gr * H + col];
  }
  if (tid < GRW) {
    int q = tid / RPW, u = tid % RPW;
    int gr = q * H + wg * RPW + u;
    s_bih0[tid] = P.b_ih0[gr]; s_bhh0[tid] = P.b_hh0[gr];
    s_bih1[tid] = P.b_ih1[gr]; s_bhh1[tid] = P.b_hh1[gr];
  }
  if (tid < 10) { s_blin[tid] = P.b_lin[tid]; s_lookup[tid] = P.lookup[tid]; }
  if (tid < RPW) {
    s_c0[tid] = P.c_init[wg * RPW + tid];
    s_c1[tid] = P.c_init[H + wg * RPW + tid];
    gstore(P.h0g + wg * RPW + tid, P.h_init[wg * RPW + tid]);
    gstore(P.h1g + wg * RPW + tid, P.h_init[H + wg * RPW + tid]);
  }

  // weight registers (192 floats): wr[0..2]=W_hh0, wr[3..5]=W_hh1, wr[6..7]=W_ih1 slots 0-1
  float wr[8][24];
#pragma unroll
  for (int slot = 0; slot < 3; ++slot) {
    int idx = wv * 3 + slot;
    int q = idx / RPW, u = idx % RPW;
    int gr = q * H + wg * RPW + u;
    const float* r0 = P.W_hh0 + (size_t)gr * H;
    const float* r1 = P.W_hh1 + (size_t)gr * H;
#pragma unroll
    for (int t = 0; t < 24; ++t) {
      int off = lane + (t << 6);
      wr[slot][t] = r0[off]; wr[3 + slot][t] = r1[off];
    }
  }
#pragma unroll
  for (int slot = 0; slot < 2; ++slot) {
    int idx = wv * 3 + slot;
    int q = idx / RPW, u = idx % RPW;
    int gr = q * H + wg * RPW + u;
    const float* r2 = P.W_ih1 + (size_t)gr * H;
#pragma unroll
    for (int t = 0; t < 24; ++t) wr[6 + slot][t] = r2[lane + (t << 6)];
  }

  unsigned ep = 1;
  flagbar(P.bar, ep++, tid, wg);

  // ---------------- main sequential loop ----------------
  for (int s = 0; s <= S_TOT; ++s) {
    // stage h0prev / h1prev
#pragma unroll
    for (int r = 0; r < 3; ++r) {
      int k = tid + r * TPB;
      s_h0[k] = gload(P.h0g + k);
      s_h1[k] = gload(P.h1g + k);
    }
    __syncthreads();

    if (s > 0) {
      int sp = s - 1;
      // logits = h1prev @ W_lin.T + b_lin  (redundant per WG, fp64 acc)
#pragma unroll
      for (int p2 = 0; p2 < 2; ++p2) {
        int l = wv + 8 * p2;
        if (l < 10) {
          double acc = 0.0;
#pragma unroll
          for (int t = 0; t < 24; ++t) {
            int off = lane + (t << 6);
            acc += (double)s_Wlin[l * H + off] * (double)s_h1[off];
          }
          acc = bsum64(acc);
          if (lane == 0) s_logits[l] = __fadd_rn((float)acc, s_blin[l]);
        }
      }
      __syncthreads();

      if (wv == 0) {
        // key_sp = threefry(key(42)=(0,42); 0, sp)   [partitionable split]
        unsigned kk0, kk1; tf2x32(0u, 42u, 0u, (unsigned)sp, kk0, kk1);
        unsigned b1, b2; tf2x32(kk0, kk1, 0u, (unsigned)lane, b1, b2);
        unsigned bits = b1 ^ b2;
        float uraw = __fsub_rn(__uint_as_float((bits >> 9) | 0x3F800000u), 1.0f);
        const float TINY = 1.17549435e-38f;
        float u  = fmaxf(TINY, __fadd_rn(uraw, TINY));
        float gum = -logf(-logf(u));
        float lg = (lane < 10) ? s_logits[lane] : 0.0f;
        float y  = (lane < 10) ? __fadd_rn(lg, gum) : -INFINITY;
        int ai = lane;
#pragma unroll
        for (int o = 1; o < 16; o <<= 1) {
          float oy = __shfl_xor(y, o); int oi = __shfl_xor(ai, o);
          if (oy > y || (oy == y && oi < ai)) { y = oy; ai = oi; }
        }
        float lm = (lane < 10) ? lg : -INFINITY;
#pragma unroll
        for (int o = 1; o < 16; o <<= 1) lm = fmaxf(lm, __shfl_xor(lm, o));
        float e2 = (lane < 10) ? expf(__fsub_rn(lg, lm)) : 0.0f;
        float ssum = e2;
#pragma unroll
        for (int o = 1; o < 16; o <<= 1) ssum = __fadd_rn(ssum, __shfl_xor(ssum, o));
        if (lane == 0) s_action = ai;
        if (wg == 0) {
          if (lane < 10) P.out[OUTP + sp * 10 + lane] = e2 / ssum;
          if (lane == 0) P.out[sp] = (float)ai;
        }
      }
      __syncthreads();
      if (tid == 0) {
        int jp = sp & 31;
        if (jp != 0) s_x[jp] = __fmul_rn(s_x[jp], s_lookup[s_action]);
      }
      __syncthreads();
    }

    if (s == S_TOT) break;
    int ii = s >> 5, jj = s & 31;
    if (jj == 0 && tid < 32) s_x[tid] = P.inputs[ii * 32 + tid];
    __syncthreads();

    // ---------- phase 1: gates0 (W_ih0·x + W_hh0·h0prev) and W_hh1·h1prev ----------
    {
      double a0 = 0, a1 = 0, a2 = 0, b0 = 0, b1 = 0, b2 = 0;
#pragma unroll
      for (int t = 0; t < 24; ++t) {
        int off = lane + (t << 6);
        double h0v = (double)s_h0[off];
        double h1v = (double)s_h1[off];
        a0 += (double)wr[0][t] * h0v;
        a1 += (double)wr[1][t] * h0v;
        a2 += (double)wr[2][t] * h0v;
        b0 += (double)wr[3][t] * h1v;
        b1 += (double)wr[4][t] * h1v;
        b2 += (double)wr[5][t] * h1v;
      }
      a0 = bsum64(a0); a1 = bsum64(a1); a2 = bsum64(a2);
      b0 = bsum64(b0); b1 = bsum64(b1); b2 = bsum64(b2);
      double xa[3];
#pragma unroll
      for (int slot = 0; slot < 3; ++slot) {
        int idx = wv * 3 + slot;
        double pp = (lane < 32)
          ? (double)s_Wih0[(idx << 5) + lane] * (double)s_x[lane] : 0.0;
#pragma unroll
        for (int o = 16; o > 0; o >>= 1) pp += __shfl_xor(pp, o);
        xa[slot] = pp;
      }
      if (lane == 0) {
        double aa[3] = {a0, a1, a2}, bb[3] = {b0, b1, b2};
#pragma unroll
        for (int slot = 0; slot < 3; ++slot) {
          int idx = wv * 3 + slot;
          float g0 = __fadd_rn(__fadd_rn(__fadd_rn((float)xa[slot], s_bih0[idx]),
                                         (float)aa[slot]), s_bhh0[idx]);
          s_gate[idx]   = g0;
          s_hh1dot[idx] = (float)bb[slot];
        }
      }
    }
    __syncthreads();
    if (tid < RPW) {
      int u = tid;
      float gi = s_gate[u], gf = s_gate[6 + u], gg = s_gate[12 + u], go = s_gate[18 + u];
      float c = __fadd_rn(__fmul_rn(sigf(gf), s_c0[u]), __fmul_rn(sigf(gi), tanhf(gg)));
      s_c0[u] = c;
      float h = __fmul_rn(sigf(go), tanhf(c));
      gstore(P.h0g + wg * RPW + u, h);
    }
    flagbar(P.bar, ep++, tid, wg);

    // ---------- phase 2: gates1 = W_ih1·h0 + (stashed W_hh1·h1prev) ----------
#pragma unroll
    for (int r = 0; r < 3; ++r) {
      int k = tid + r * TPB;
      s_h0[k] = gload(P.h0g + k);
    }
    __syncthreads();
    {
      double a0 = 0, a1 = 0, a2 = 0;
#pragma unroll
      for (int t = 0; t < 24; ++t) {
        int off = lane + (t << 6);
        double hv = (double)s_h0[off];
        a0 += (double)wr[6][t] * hv;
        a1 += (double)wr[7][t] * hv;
        a2 += (double)s_W3[wv * H + off] * hv;
      }
      a0 = bsum64(a0); a1 = bsum64(a1); a2 = bsum64(a2);
      if (lane == 0) {
        double aa[3] = {a0, a1, a2};
#pragma unroll
        for (int slot = 0; slot < 3; ++slot) {
          int idx = wv * 3 + slot;
          s_gate[idx] = __fadd_rn(__fadd_rn(__fadd_rn((float)aa[slot], s_bih1[idx]),
                                            s_hh1dot[idx]), s_bhh1[idx]);
        }
      }
    }
    __syncthreads();
    if (tid < RPW) {
      int u = tid;
      float gi = s_gate[u], gf = s_gate[6 + u], gg = s_gate[12 + u], go = s_gate[18 + u];
      float c = __fadd_rn(__fmul_rn(sigf(gf), s_c1[u]), __fmul_rn(sigf(gi), tanhf(gg)));
      s_c1[u] = c;
      float h = __fmul_rn(sigf(go), tanhf(c));
      gstore(P.h1g + wg * RPW + u, h);
    }
    flagbar(P.bar, ep++, tid, wg);
  }
}

extern "C" void kernel_launch(void* const* d_in, const int* in_sizes, int n_in,
                              void* d_out, int out_size, void* d_ws, size_t ws_size,
                              hipStream_t stream) {
  (void)in_sizes; (void)n_in; (void)out_size; (void)ws_size;
  Params p;
  p.inputs = (const float*)d_in[0];
  p.h_init = (const float*)d_in[1];
  p.c_init = (const float*)d_in[2];
  p.W_ih0  = (const float*)d_in[3];
  p.W_hh0  = (const float*)d_in[4];
  p.b_ih0  = (const float*)d_in[5];
  p.b_hh0  = (const float*)d_in[6];
  p.W_ih1  = (const float*)d_in[7];
  p.W_hh1  = (const float*)d_in[8];
  p.b_ih1  = (const float*)d_in[9];
  p.b_hh1  = (const float*)d_in[10];
  p.W_lin  = (const float*)d_in[11];
  p.b_lin  = (const float*)d_in[12];
  p.lookup = (const float*)d_in[13];
  p.out    = (float*)d_out;
  float* ws = (float*)d_ws;
  p.h0g = ws;
  p.h1g = ws + H;
  p.bar = (unsigned*)(ws + 2 * H);

  // opt-in for >64 KB dynamic LDS (idempotent; host-side, graph-capture safe)
  hipFuncSetAttribute((const void*)lstm_persistent,
                      hipFuncAttributeMaxDynamicSharedMemorySize, SMEM_BYTES);
  hipLaunchKernelGGL(lstm_persistent, dim3(NWG), dim3(TPB), SMEM_BYTES, stream, p);
}